// Round 6
// baseline (86.505 us; speedup 1.0000x reference)
//
#include <hip/hip_runtime.h>
#include <stdint.h>

#define T_STEPS 2048
#define NCHUNK  86            // 85 full 24-step chunks + one 8-step tail chunk
#define LARGEF  1.0e9f
typedef unsigned long long u64;
typedef unsigned uint2v __attribute__((ext_vector_type(2)));

__device__ __forceinline__ int par6(int x) { return __builtin_popcount((unsigned)x) & 1; }

// dual-basis functionals C and exchange masks m={1,2,7,15,16,32} (verified r2-r5)
constexpr int CARR[6] = {5, 6, 12, 8, 16, 32};

constexpr u64 ptab_gen(int C) {
  u64 r = 0;
  for (int s = 0; s < 64; ++s) r |= (u64)(__builtin_popcount((unsigned)(s & C)) & 1) << s;
  return r;
}
constexpr u64 PTAB[6] = {ptab_gen(5), ptab_gen(6), ptab_gen(12),
                         ptab_gen(8), ptab_gen(16), ptab_gen(32)};

template<int CTRL>
__device__ __forceinline__ float xdpp(float x) {
  return __int_as_float(__builtin_amdgcn_update_dpp(0, __float_as_int(x), CTRL, 0xF, 0xF, true));
}
template<int CTRL>
__device__ __forceinline__ unsigned xdpp_u(unsigned x) {
  return (unsigned)__builtin_amdgcn_update_dpp(0, (int)x, CTRL, 0xF, 0xF, true);
}

__device__ __forceinline__ unsigned exch16_u(unsigned x, bool use_rx) {
#if __has_builtin(__builtin_amdgcn_permlane16_swap)
  uint2v r = __builtin_amdgcn_permlane16_swap(x, x, false, false);
  return use_rx ? r.x : r.y;
#else
  (void)use_rx;
  return (unsigned)__builtin_amdgcn_ds_swizzle((int)x, 0x401F);
#endif
}
__device__ __forceinline__ unsigned exch32_u(unsigned x, bool use_rx) {
#if __has_builtin(__builtin_amdgcn_permlane32_swap)
  uint2v r = __builtin_amdgcn_permlane32_swap(x, x, false, false);
  return use_rx ? r.x : r.y;
#else
  (void)use_rx;
  return (unsigned)__shfl_xor((int)x, 32, 64);
#endif
}
__device__ __forceinline__ float exch16f(float x, bool use_rx) {
  return __uint_as_float(exch16_u(__float_as_uint(x), use_rx));
}
__device__ __forceinline__ float exch32f(float x, bool use_rx) {
  return __uint_as_float(exch32_u(__float_as_uint(x), use_rx));
}

struct Ctx {
  float sae[6], sbe[6];
  unsigned pdu[6];   // decoded-bit constant per phase (0/1)
  bool pd[6];        // own-pred LSB parity (tie semantics)
  bool use_rx16, use_rx32;
};

// ---- hoisted branch metrics for a chunk (independent ILP block) ----
template<int N>
__device__ __forceinline__ void bmcalc(const float4 (&fy)[12], float (&bm)[24], const Ctx& cx) {
#pragma unroll
  for (int k = 0; k < N; ++k) {
    const int ph = k % 6;
    const float y0 = (k & 1) ? fy[k >> 1].z : fy[k >> 1].x;
    const float y1 = (k & 1) ? fy[k >> 1].w : fy[k >> 1].y;
    bm[k] = fmaf(cx.sae[ph], y0, cx.sbe[ph] * y1);   // bit-exact vs ref
  }
}

// ---- N ACS steps, start phase 0; word = [path bits 6..][anc 0..5] ----
template<int N, int K>
__device__ __forceinline__ void fsteps(float& cum, unsigned& word,
                                       const float (&bm)[24], const Ctx& cx) {
  if constexpr (K < N) {
    constexpr int ph = K % 6;
    float ex; unsigned exw;
    if constexpr (ph == 0)      { ex = xdpp<0xB1>(cum);  exw = xdpp_u<0xB1>(word); }   // xor 1
    else if constexpr (ph == 1) { ex = xdpp<0x4E>(cum);  exw = xdpp_u<0x4E>(word); }   // xor 2
    else if constexpr (ph == 2) { ex = xdpp<0x141>(cum); exw = xdpp_u<0x141>(word); }  // xor 7
    else if constexpr (ph == 3) { ex = xdpp<0x140>(cum); exw = xdpp_u<0x140>(word); }  // xor 15
    else if constexpr (ph == 4) { ex = exch16f(cum, cx.use_rx16); exw = exch16_u(word, cx.use_rx16); } // xor 16
    else                        { ex = exch32f(cum, cx.use_rx32); exw = exch32_u(word, cx.use_rx32); } // xor 32
    const float cA = cum + bm[K];   // own-pred candidate
    const float cB = ex - bm[K];    // partner-pred candidate
    // take partner: strict if own pred even (tie->own), >= if own pred odd (tie->partner)
    const bool tp = cx.pd[ph] ? !(cA < cB) : (cB < cA);
    word = (tp ? exw : word) | (cx.pdu[ph] << (6 + K));
    cum = fminf(cA, cB);
    fsteps<N, K + 1>(cum, word, bm, cx);
  }
}

__global__ __launch_bounds__(64, 1) void viterbi_kernel(const float* __restrict__ in,
                                                        float* __restrict__ out) {
  __shared__ unsigned tbf[NCHUNK * 64];    // 21.5 KB flushed path/anc words

  const int b = blockIdx.x;
  const int lane = threadIdx.x;
  const float4* yrow4 = (const float4*)(in + (size_t)b * (2 * T_STEPS));  // 1024 float4

  // ---- per-phase lane constants ----
  Ctx cx;
#pragma unroll
  for (int ph = 0; ph < 6; ++ph) {
    const int pdv = par6(lane & CARR[ph]);
    int t = 0;
#pragma unroll
    for (int j = 0; j < 5; ++j) t |= par6(lane & CARR[(ph + 1 + j) % 6]) << j;
    t |= pdv << 5;
    const float sa = 1.0f - 2.0f * (float)par6(t & 45);   // poly 1011011
    const float sb = 1.0f - 2.0f * (float)par6(t & 60);   // poly 1111001
    cx.sae[ph] = pdv ? -sa : sa;
    cx.sbe[ph] = pdv ? -sb : sb;
    cx.pd[ph] = (pdv != 0);
    cx.pdu[ph] = (unsigned)pdv;
  }
  // ---- probe permlane swap output-register convention ----
  {
    const bool oddrow = ((lane >> 4) & 1) != 0;
    const bool lanehi = lane >= 32;
#if __has_builtin(__builtin_amdgcn_permlane16_swap)
    uint2v p16 = __builtin_amdgcn_permlane16_swap((unsigned)lane, (unsigned)lane, false, false);
    const bool rxo = ((unsigned)__builtin_amdgcn_readlane((int)p16.x, 0) == 16u);
    cx.use_rx16 = oddrow ^ rxo;
#else
    cx.use_rx16 = false;
#endif
#if __has_builtin(__builtin_amdgcn_permlane32_swap)
    uint2v p32 = __builtin_amdgcn_permlane32_swap((unsigned)lane, (unsigned)lane, false, false);
    const bool rxh = ((unsigned)__builtin_amdgcn_readlane((int)p32.x, 0) == 32u);
    cx.use_rx32 = lanehi ^ rxh;
#else
    cx.use_rx32 = false;
#endif
  }

  // ---- forward ACS: double-buffered broadcast y prefetch, hoisted bms ----
  float cum = (lane == 0) ? 0.0f : LARGEF;
  unsigned word = (unsigned)lane;
  float4 buf0[12], buf1[12];
  float bm[24];
#pragma unroll
  for (int j = 0; j < 12; ++j) buf0[j] = yrow4[j];           // chunk 0

  for (int cc = 0; cc < 42; ++cc) {
    const int c0 = 2 * cc;
#pragma unroll
    for (int j = 0; j < 12; ++j) buf1[j] = yrow4[12 * (c0 + 1) + j];   // prefetch c0+1
    bmcalc<24>(buf0, bm, cx);
    fsteps<24, 0>(cum, word, bm, cx);
    tbf[c0 * 64 + lane] = word; word = (unsigned)lane;
#pragma unroll
    for (int j = 0; j < 12; ++j) buf0[j] = yrow4[12 * (c0 + 2) + j];   // prefetch c0+2
    bmcalc<24>(buf1, bm, cx);
    fsteps<24, 0>(cum, word, bm, cx);
    tbf[(c0 + 1) * 64 + lane] = word; word = (unsigned)lane;
  }
  // buf0 = chunk 84; prefetch tail region [1012..1023] (tail data at buf1[8..11])
#pragma unroll
  for (int j = 0; j < 12; ++j) buf1[j] = yrow4[1012 + j];
  bmcalc<24>(buf0, bm, cx);
  fsteps<24, 0>(cum, word, bm, cx);
  tbf[84 * 64 + lane] = word; word = (unsigned)lane;
  {  // tail: 8 steps (2040..2047), phase 0 start (2040%6==0)
    float4 ft[12];
#pragma unroll
    for (int j = 0; j < 4; ++j) ft[j] = buf1[8 + j];
    bmcalc<8>(ft, bm, cx);
    fsteps<8, 0>(cum, word, bm, cx);
    tbf[85 * 64 + lane] = word;
  }

  // ---- terminal argmin over true states (tie -> smallest state) ----
  // final labeling = phase 2048%6 = 2: state bit j from C[(2+j)%6] = {12,8,16,32,5,6}
  const int stf = par6(lane & 12) | (par6(lane & 8) << 1) | (par6(lane & 16) << 2) |
                  (par6(lane & 32) << 3) | (par6(lane & 5) << 4) | (par6(lane & 6) << 5);
  float v = cum; int bs = stf; int bl = lane;
#pragma unroll
  for (int off = 32; off >= 1; off >>= 1) {
    const float ov = __shfl_xor(v, off, 64);
    const int os = __shfl_xor(bs, off, 64);
    const int ol = __shfl_xor(bl, off, 64);
    if (ov < v || (ov == v && os < bs)) { v = ov; bs = os; bl = ol; }
  }
  int lam = __builtin_amdgcn_readfirstlane(bl);

  // ---- reconstruction: 86 chunk hops, prefetched rows, bits stored per hop ----
  const size_t ob = (size_t)b * T_STEPS;
  unsigned row = tbf[85 * 64 + lane];
  for (int c = 85; c >= 0; --c) {
    unsigned nrow = 0;
    if (c > 0) nrow = tbf[(c - 1) * 64 + lane];          // prefetch (addr indep of lam)
    const unsigned w = (unsigned)__builtin_amdgcn_readlane((int)row, lam);
    const int nb = (c == 85) ? 8 : 24;
    if (lane < nb) out[ob + c * 24 + lane] = (float)((w >> (6 + lane)) & 1u);
    lam = (int)(w & 63u);
    row = nrow;
  }
}

extern "C" void kernel_launch(void* const* d_in, const int* in_sizes, int n_in,
                              void* d_out, int out_size, void* d_ws, size_t ws_size,
                              hipStream_t stream) {
  const float* in = (const float*)d_in[0];
  float* out = (float*)d_out;
  (void)in_sizes; (void)n_in; (void)out_size; (void)d_ws; (void)ws_size;
  viterbi_kernel<<<dim3(512), dim3(64), 0, stream>>>(in, out);
}

// Round 7
// 74.788 us; speedup vs baseline: 1.1567x; 1.1567x over previous
//
#include <hip/hip_runtime.h>
#include <stdint.h>

#define T_STEPS 2048
#define NCHUNK  86            // 85 full 24-step chunks + one 8-step tail chunk
#define LARGEF  1.0e9f
typedef unsigned long long u64;
typedef unsigned uint2v __attribute__((ext_vector_type(2)));

__device__ __forceinline__ int par6(int x) { return __builtin_popcount((unsigned)x) & 1; }

// dual-basis functionals C; exchange masks m={1,2,7,15,16,32} (verified r2-r6)
constexpr int CARR[6] = {5, 6, 12, 8, 16, 32};

template<int CTRL>
__device__ __forceinline__ float xdpp(float x) {
  return __int_as_float(__builtin_amdgcn_update_dpp(0, __float_as_int(x), CTRL, 0xF, 0xF, true));
}
template<int CTRL>
__device__ __forceinline__ unsigned xdpp_u(unsigned x) {
  return (unsigned)__builtin_amdgcn_update_dpp(0, (int)x, CTRL, 0xF, 0xF, true);
}

// select by uniform 64-bit wave mask (SGPR pair): bit=1 -> take b_true
__device__ __forceinline__ unsigned selmask_u(unsigned a_false, unsigned b_true, u64 m) {
  unsigned out;
  asm("v_cndmask_b32 %0, %1, %2, %3" : "=v"(out) : "v"(a_false), "v"(b_true), "s"(m));
  return out;
}

__device__ __forceinline__ unsigned exch16_u(unsigned x, u64 mrx) {
#if __has_builtin(__builtin_amdgcn_permlane16_swap)
  uint2v r = __builtin_amdgcn_permlane16_swap(x, x, false, false);
  return selmask_u(r.y, r.x, mrx);
#else
  (void)mrx;
  return (unsigned)__builtin_amdgcn_ds_swizzle((int)x, 0x401F);
#endif
}
__device__ __forceinline__ unsigned exch32_u(unsigned x, u64 mrx) {
#if __has_builtin(__builtin_amdgcn_permlane32_swap)
  uint2v r = __builtin_amdgcn_permlane32_swap(x, x, false, false);
  return selmask_u(r.y, r.x, mrx);
#else
  (void)mrx;
  return (unsigned)__shfl_xor((int)x, 32, 64);
#endif
}
__device__ __forceinline__ float exch16_f(float x, u64 mrx) {
  return __uint_as_float(exch16_u(__float_as_uint(x), mrx));
}
__device__ __forceinline__ float exch32_f(float x, u64 mrx) {
  return __uint_as_float(exch32_u(__float_as_uint(x), mrx));
}

struct Ctx {
  float sae[6], sbe[6];
  unsigned pdu[6];   // decoded-bit constant per phase (0/1)
  u64 pdm[6];        // uniform mask: lanes with odd own-pred parity
  u64 mrx16, mrx32;  // uniform masks: lanes taking r.x from permlane swaps
};

// ---- hoisted branch metrics for a chunk (independent ILP block) ----
template<int N>
__device__ __forceinline__ void bmcalc(const float4 (&fy)[12], float (&bm)[24], const Ctx& cx) {
#pragma unroll
  for (int k = 0; k < N; ++k) {
    const int ph = k % 6;
    const float y0 = (k & 1) ? fy[k >> 1].z : fy[k >> 1].x;
    const float y1 = (k & 1) ? fy[k >> 1].w : fy[k >> 1].y;
    bm[k] = fmaf(cx.sae[ph], y0, cx.sbe[ph] * y1);   // bit-exact vs ref
  }
}

// ---- N ACS steps, start phase 0; word = [path bits 6..][anc 0..5] ----
template<int N, int K>
__device__ __forceinline__ void fsteps(float& cum, unsigned& word,
                                       const float (&bm)[24], const Ctx& cx) {
  if constexpr (K < N) {
    constexpr int ph = K % 6;
    float ex; unsigned exw;
    if constexpr (ph == 0)      { ex = xdpp<0xB1>(cum);  exw = xdpp_u<0xB1>(word); }   // xor 1
    else if constexpr (ph == 1) { ex = xdpp<0x4E>(cum);  exw = xdpp_u<0x4E>(word); }   // xor 2
    else if constexpr (ph == 2) { ex = xdpp<0x141>(cum); exw = xdpp_u<0x141>(word); }  // xor 7
    else if constexpr (ph == 3) { ex = xdpp<0x140>(cum); exw = xdpp_u<0x140>(word); }  // xor 15
    else if constexpr (ph == 4) { ex = exch16_f(cum, cx.mrx16); exw = exch16_u(word, cx.mrx16); } // xor 16
    else                        { ex = exch32_f(cum, cx.mrx32); exw = exch32_u(word, cx.mrx32); } // xor 32
    const float cA = cum + bm[K];   // own-pred candidate
    const float cB = ex - bm[K];    // partner-pred candidate
    // take-partner: strict if own pred even (tie->own), >= if own pred odd (tie->partner)
    const u64 b1 = __ballot(cB < cA);
    const u64 b2 = __ballot(cA < cB);
    const u64 tpm = (b1 & ~cx.pdm[ph]) | (cx.pdm[ph] & ~b2);
    word = selmask_u(word, exw, tpm) | (cx.pdu[ph] << (6 + K));
    cum = fminf(cA, cB);
    fsteps<N, K + 1>(cum, word, bm, cx);
  }
}

__global__ __launch_bounds__(64, 1) void viterbi_kernel(const float* __restrict__ in,
                                                        float* __restrict__ out) {
  __shared__ float y_lds[2 * T_STEPS];     // 16 KB staged input row
  __shared__ unsigned tbf[NCHUNK * 64];    // 21.5 KB flushed path/anc words

  const int b = blockIdx.x;
  const int lane = threadIdx.x;
  const float* yrow = in + (size_t)b * (2 * T_STEPS);

  // ---- stage y into LDS (coalesced float4) ----
  {
    const float4* g = (const float4*)yrow;
    float4* l = (float4*)y_lds;
#pragma unroll
    for (int i = 0; i < 16; ++i) l[i * 64 + lane] = g[i * 64 + lane];
  }
  __syncthreads();

  // ---- per-phase lane constants ----
  Ctx cx;
#pragma unroll
  for (int ph = 0; ph < 6; ++ph) {
    const int pdv = par6(lane & CARR[ph]);
    int t = 0;
#pragma unroll
    for (int j = 0; j < 5; ++j) t |= par6(lane & CARR[(ph + 1 + j) % 6]) << j;
    t |= pdv << 5;
    const float sa = 1.0f - 2.0f * (float)par6(t & 45);   // poly 1011011
    const float sb = 1.0f - 2.0f * (float)par6(t & 60);   // poly 1111001
    cx.sae[ph] = pdv ? -sa : sa;
    cx.sbe[ph] = pdv ? -sb : sb;
    cx.pdu[ph] = (unsigned)pdv;
    cx.pdm[ph] = __ballot(pdv != 0);
  }
  // ---- probe permlane swap output-register convention -> uniform masks ----
  {
    const u64 ODD16 = 0xFFFF0000FFFF0000ull;   // lanes with (lane>>4)&1 == 1
    const u64 HI32  = 0xFFFFFFFF00000000ull;   // lanes >= 32
#if __has_builtin(__builtin_amdgcn_permlane16_swap)
    uint2v p16 = __builtin_amdgcn_permlane16_swap((unsigned)lane, (unsigned)lane, false, false);
    const bool rxo = ((unsigned)__builtin_amdgcn_readlane((int)p16.x, 0) == 16u);
    cx.mrx16 = rxo ? ~ODD16 : ODD16;
#else
    cx.mrx16 = 0;
#endif
#if __has_builtin(__builtin_amdgcn_permlane32_swap)
    uint2v p32 = __builtin_amdgcn_permlane32_swap((unsigned)lane, (unsigned)lane, false, false);
    const bool rxh = ((unsigned)__builtin_amdgcn_readlane((int)p32.x, 0) == 32u);
    cx.mrx32 = rxh ? ~HI32 : HI32;
#else
    cx.mrx32 = 0;
#endif
  }

  // ---- forward ACS: LDS->reg double-buffered prefetch, hoisted bm blocks ----
  float cum = (lane == 0) ? 0.0f : LARGEF;
  unsigned word = (unsigned)lane;
  float bm[24];
  float4 cur[12], nxt[12];
  const float4* y4 = (const float4*)y_lds;
#pragma unroll
  for (int j = 0; j < 12; ++j) cur[j] = y4[j];               // chunk 0
  for (int cc = 0; cc < 42; ++cc) {
    const int c0 = 2 * cc;
    bmcalc<24>(cur, bm, cx);
#pragma unroll
    for (int j = 0; j < 12; ++j) nxt[j] = y4[12 * (c0 + 1) + j];   // prefetch c0+1
    fsteps<24, 0>(cum, word, bm, cx);
    tbf[c0 * 64 + lane] = word; word = (unsigned)lane;
    bmcalc<24>(nxt, bm, cx);
#pragma unroll
    for (int j = 0; j < 12; ++j) cur[j] = y4[12 * (c0 + 2) + j];   // prefetch c0+2
    fsteps<24, 0>(cum, word, bm, cx);
    tbf[(c0 + 1) * 64 + lane] = word; word = (unsigned)lane;
  }
  // cur = chunk 84; tail (steps 2040..2047) = float4 idx 1020..1023
  bmcalc<24>(cur, bm, cx);
#pragma unroll
  for (int j = 0; j < 4; ++j) nxt[j] = y4[1020 + j];
  fsteps<24, 0>(cum, word, bm, cx);
  tbf[84 * 64 + lane] = word; word = (unsigned)lane;
  bmcalc<8>(nxt, bm, cx);
  fsteps<8, 0>(cum, word, bm, cx);
  tbf[85 * 64 + lane] = word;

  // ---- terminal argmin over true states (tie -> smallest state) ----
  // final labeling = phase 2048%6 = 2: state bit j from C[(2+j)%6] = {12,8,16,32,5,6}
  const int stf = par6(lane & 12) | (par6(lane & 8) << 1) | (par6(lane & 16) << 2) |
                  (par6(lane & 32) << 3) | (par6(lane & 5) << 4) | (par6(lane & 6) << 5);
  float v = cum; int bs = stf; int bl = lane;
#pragma unroll
  for (int off = 32; off >= 1; off >>= 1) {
    const float ov = __shfl_xor(v, off, 64);
    const int os = __shfl_xor(bs, off, 64);
    const int ol = __shfl_xor(bl, off, 64);
    if (ov < v || (ov == v && os < bs)) { v = ov; bs = os; bl = ol; }
  }
  int lam = __builtin_amdgcn_readfirstlane(bl);

  // ---- reconstruction: 86 chunk hops, prefetched rows, bits stored per hop ----
  const size_t ob = (size_t)b * T_STEPS;
  unsigned row = tbf[85 * 64 + lane];
  for (int c = 85; c >= 0; --c) {
    unsigned nrow = 0;
    if (c > 0) nrow = tbf[(c - 1) * 64 + lane];          // prefetch (addr indep of lam)
    const unsigned w = (unsigned)__builtin_amdgcn_readlane((int)row, lam);
    const int nb = (c == 85) ? 8 : 24;
    if (lane < nb) out[ob + c * 24 + lane] = (float)((w >> (6 + lane)) & 1u);
    lam = (int)(w & 63u);
    row = nrow;
  }
}

extern "C" void kernel_launch(void* const* d_in, const int* in_sizes, int n_in,
                              void* d_out, int out_size, void* d_ws, size_t ws_size,
                              hipStream_t stream) {
  const float* in = (const float*)d_in[0];
  float* out = (float*)d_out;
  (void)in_sizes; (void)n_in; (void)out_size; (void)d_ws; (void)ws_size;
  viterbi_kernel<<<dim3(512), dim3(64), 0, stream>>>(in, out);
}